// Round 2
// 698.916 us; speedup vs baseline: 1.0971x; 1.0971x over previous
//
#include <hip/hip_runtime.h>
#include <stdint.h>

#define BATCH  1024
#define DMODEL 4096
#define DSTATE 16
#define DTRANK 256
#define NPROJ  288   // DTRANK + 2*DSTATE

typedef short  short8 __attribute__((ext_vector_type(8)));
typedef __bf16 bf16x8 __attribute__((ext_vector_type(8)));
typedef float  f32x4  __attribute__((ext_vector_type(4)));

static __device__ __forceinline__ short f2bf(float f) {
  uint32_t u = __float_as_uint(f);
  u = (u + 0x7fffu + ((u >> 16) & 1u)) >> 16;   // RNE
  return (short)u;
}
static __device__ __forceinline__ float bf2f(short s) {
  return __uint_as_float(((uint32_t)(uint16_t)s) << 16);
}

// async global->LDS, 16B per lane; LDS dest = wave-uniform base + lane*16
static __device__ __forceinline__ void gl_lds16(const void* g, void* lds) {
  __builtin_amdgcn_global_load_lds(
      (const __attribute__((address_space(1))) void*)g,
      (__attribute__((address_space(3))) void*)lds, 16, 0, 0);
}

// ---------------- conversion kernels (fp32 -> bf16 hi [+ lo residual]) --------
template<bool LO>
__global__ __launch_bounds__(256) void cvt_hilo(const float* __restrict__ in,
                                                short* __restrict__ outH,
                                                short* __restrict__ outL, int n8) {
  const int i = blockIdx.x * 256 + threadIdx.x;
  if (i >= n8) return;
  const float4* p = (const float4*)in + (size_t)i * 2;
  float4 v0 = p[0], v1 = p[1];
  float vv[8] = {v0.x, v0.y, v0.z, v0.w, v1.x, v1.y, v1.z, v1.w};
  short hh[8], ll[8];
  #pragma unroll
  for (int j = 0; j < 8; ++j) {
    hh[j] = f2bf(vv[j]);
    ll[j] = f2bf(vv[j] - bf2f(hh[j]));
  }
  ((short8*)outH)[i] = *(const short8*)hh;
  if (LO) ((short8*)outL)[i] = *(const short8*)ll;
}

// slice xp[:, :256] (ld=288) -> hi/lo bf16 with ld=256
__global__ __launch_bounds__(256) void cvt_xp(const float* __restrict__ xp,
                                              short* __restrict__ outH,
                                              short* __restrict__ outL) {
  const int i = blockIdx.x * 256 + threadIdx.x;   // 32768 groups of 8
  const int b = i >> 5, c = (i & 31) << 3;
  const float* p = xp + (size_t)b * NPROJ + c;
  float4 v0 = *(const float4*)p, v1 = *(const float4*)(p + 4);
  float vv[8] = {v0.x, v0.y, v0.z, v0.w, v1.x, v1.y, v1.z, v1.w};
  short hh[8], ll[8];
  #pragma unroll
  for (int j = 0; j < 8; ++j) {
    hh[j] = f2bf(vv[j]);
    ll[j] = f2bf(vv[j] - bf2f(hh[j]));
  }
  ((short8*)outH)[i] = *(const short8*)hh;
  ((short8*)outL)[i] = *(const short8*)ll;
}

// ---- partial reduction: out[i4] = sum_{j<N} in[j*stride + i4] (float4) ------
template<int N>
__global__ __launch_bounds__(256) void reduce_add(const float* __restrict__ in,
                                                  size_t stride,
                                                  float* __restrict__ out, int n4) {
  const int i = blockIdx.x * 256 + threadIdx.x;
  if (i >= n4) return;
  float4 s = ((const float4*)in)[i];
  #pragma unroll
  for (int j = 1; j < N; ++j) {
    float4 v = ((const float4*)(in + (size_t)j * stride))[i];
    s.x += v.x; s.y += v.y; s.z += v.z; s.w += v.w;
  }
  ((float4*)out)[i] = s;
}

// ---------------- m97-style bf16 GEMM: C[m][n] = sum_k A[m][k]*B[n][k] -------
// 128x128 tile, BK=32, 256 thr = 4 waves (2x2 of 64x64), global_load_lds width16.
// SPLIT: A/B given as hi+lo bf16 pairs, 3 MFMAs (HH+HL+LH) for ~fp32 accuracy.
// Split-K: block z computes K-chunk [z*k_len, (z+1)*k_len) and stores its
// partial to C + z*cz_stride (plain stores, deterministic; no atomics).
template<bool SPLIT>
__global__ __launch_bounds__(256) void gemm_lds(
    const short* __restrict__ AH, const short* __restrict__ AL, int lda,
    const short* __restrict__ BH, const short* __restrict__ BL, int ldb, int nB,
    float* __restrict__ C, int ldc, size_t cz_stride, int k_len)
{
  const int bn = blockIdx.x, bm = blockIdx.y;
  const int kbase0 = blockIdx.z * k_len;
  float* __restrict__ Cz = C + (size_t)blockIdx.z * cz_stride;
  const int tid = threadIdx.x;
  const int lane = tid & 63, wave = tid >> 6;
  const int wm = (wave & 1) << 6, wn = (wave >> 1) << 6;
  const int row = lane & 15, quad = lane >> 4;

  // [ko<4][idx<128][j<8] bf16; chunk c=(ko<<7)|idx is 16B, fragment-contiguous
  __shared__ short AsH[4096], BsH[4096];
  __shared__ short AsL[SPLIT ? 4096 : 4], BsL[SPLIT ? 4096 : 4];

  f32x4 acc[4][4];
  #pragma unroll
  for (int i = 0; i < 4; ++i)
    #pragma unroll
    for (int j = 0; j < 4; ++j) acc[i][j] = (f32x4){0.f, 0.f, 0.f, 0.f};

  // staging chunks: c = wave*128 + it*64 + lane, it in {0,1}
  const int c0 = (wave << 7) + lane, c1 = c0 + 64;
  const int m0 = c0 & 127, k0 = c0 >> 7;
  const int m1 = c1 & 127, k1 = c1 >> 7;
  const size_t arow0 = (size_t)((bm << 7) + m0) * lda + (k0 << 3);
  const size_t arow1 = (size_t)((bm << 7) + m1) * lda + (k1 << 3);
  const size_t brow0 = (size_t)((bn << 7) + m0) * ldb + (k0 << 3);
  const size_t brow1 = (size_t)((bn << 7) + m1) * ldb + (k1 << 3);
  short* lA0 = &AsH[c0 << 3]; short* lA1 = &AsH[c1 << 3];
  short* lB0 = &BsH[c0 << 3]; short* lB1 = &BsH[c1 << 3];
  short* lAL0 = nullptr; short* lAL1 = nullptr;
  short* lBL0 = nullptr; short* lBL1 = nullptr;
  if constexpr (SPLIT) {
    lAL0 = &AsL[c0 << 3]; lAL1 = &AsL[c1 << 3];
    lBL0 = &BsL[c0 << 3]; lBL1 = &BsL[c1 << 3];
  }

  const int nsteps = k_len >> 5;
  for (int ks = 0; ks < nsteps; ++ks) {
    const int kb = kbase0 + (ks << 5);
    __syncthreads();
    gl_lds16(AH + arow0 + kb, lA0);
    gl_lds16(AH + arow1 + kb, lA1);
    gl_lds16(BH + brow0 + kb, lB0);
    gl_lds16(BH + brow1 + kb, lB1);
    if constexpr (SPLIT) {
      gl_lds16(AL + arow0 + kb, lAL0);
      gl_lds16(AL + arow1 + kb, lAL1);
      gl_lds16(BL + brow0 + kb, lBL0);
      gl_lds16(BL + brow1 + kb, lBL1);
    }
    __syncthreads();

    short8 aH[4], bH[4], aL[4], bL[4];
    #pragma unroll
    for (int i = 0; i < 4; ++i) {
      const int ao = (((quad << 7) + wm + (i << 4) + row) << 3);
      const int bo = (((quad << 7) + wn + (i << 4) + row) << 3);
      aH[i] = *(short8*)&AsH[ao];
      bH[i] = *(short8*)&BsH[bo];
      if constexpr (SPLIT) {
        aL[i] = *(short8*)&AsL[ao];
        bL[i] = *(short8*)&BsL[bo];
      }
    }
    #pragma unroll
    for (int mi = 0; mi < 4; ++mi)
      #pragma unroll
      for (int ni = 0; ni < 4; ++ni) {
        acc[mi][ni] = __builtin_amdgcn_mfma_f32_16x16x32_bf16(
            __builtin_bit_cast(bf16x8, aH[mi]), __builtin_bit_cast(bf16x8, bH[ni]),
            acc[mi][ni], 0, 0, 0);
        if constexpr (SPLIT) {
          acc[mi][ni] = __builtin_amdgcn_mfma_f32_16x16x32_bf16(
              __builtin_bit_cast(bf16x8, aH[mi]), __builtin_bit_cast(bf16x8, bL[ni]),
              acc[mi][ni], 0, 0, 0);
          acc[mi][ni] = __builtin_amdgcn_mfma_f32_16x16x32_bf16(
              __builtin_bit_cast(bf16x8, aL[mi]), __builtin_bit_cast(bf16x8, bH[ni]),
              acc[mi][ni], 0, 0, 0);
        }
      }
  }

  // ---- epilogue: C/D layout col=lane&15, row=quad*4+reg ----
  #pragma unroll
  for (int mi = 0; mi < 4; ++mi) {
    #pragma unroll
    for (int ni = 0; ni < 4; ++ni) {
      const int rbase = (bm << 7) + wm + (mi << 4) + (quad << 2);
      const int cg = (bn << 7) + wn + (ni << 4) + row;
      if (cg < nB) {
        #pragma unroll
        for (int r = 0; r < 4; ++r) {
          Cz[(size_t)(rbase + r) * ldc + cg] = acc[mi][ni][r];
        }
      }
    }
  }
}

// delta = softplus(dP0+dP1+bdt[d]);
// h_new[b,d,n] = exp(delta*A[n])*h + delta*B[b,n]*x[b,d];  y_pre = sum_n C[b,n]*h_new + D[d]*x
__global__ __launch_bounds__(256) void ssm_update(
    const float* __restrict__ x, const float* __restrict__ h,
    const float* __restrict__ xp, const float* __restrict__ dP,
    const float* __restrict__ bdt,
    const float* __restrict__ A_log, const float* __restrict__ Dv,
    float* __restrict__ out, short* __restrict__ ypre)
{
  const int b = blockIdx.y;
  const int d = (blockIdx.x << 8) + threadIdx.x;
  __shared__ float Bs[DSTATE], Cs[DSTATE], Aa[DSTATE];
  if (threadIdx.x < DSTATE) {
    const int t = threadIdx.x;
    Bs[t] = xp[b * NPROJ + DTRANK + t];
    Cs[t] = xp[b * NPROJ + DTRANK + DSTATE + t];
    Aa[t] = -__expf(A_log[t]);
  }
  __syncthreads();
  const size_t bd = (size_t)b * DMODEL + d;
  // fold split-K partials + bias + softplus (exact elementwise)
  const float traw = dP[bd] + dP[bd + (size_t)BATCH * DMODEL] + bdt[d];
  const float dl = fmaxf(traw, 0.f) + log1pf(__expf(-fabsf(traw)));
  const float xv = x[bd];
  const float4* hp = (const float4*)(h + bd * 16);
  float4* ho = (float4*)(out + (size_t)BATCH * DMODEL + bd * 16);
  float y = 0.f;
  #pragma unroll
  for (int g = 0; g < 4; ++g) {
    float4 hv = hp[g];
    float4 o;
    o.x = __expf(dl * Aa[4*g+0]) * hv.x + dl * Bs[4*g+0] * xv; y = fmaf(Cs[4*g+0], o.x, y);
    o.y = __expf(dl * Aa[4*g+1]) * hv.y + dl * Bs[4*g+1] * xv; y = fmaf(Cs[4*g+1], o.y, y);
    o.z = __expf(dl * Aa[4*g+2]) * hv.z + dl * Bs[4*g+2] * xv; y = fmaf(Cs[4*g+2], o.z, y);
    o.w = __expf(dl * Aa[4*g+3]) * hv.w + dl * Bs[4*g+3] * xv; y = fmaf(Cs[4*g+3], o.w, y);
    ho[g] = o;
  }
  y = fmaf(Dv[d], xv, y);
  ypre[bd] = f2bf(y);
}

extern "C" void kernel_launch(void* const* d_in, const int* in_sizes, int n_in,
                              void* d_out, int out_size, void* d_ws, size_t ws_size,
                              hipStream_t stream)
{
  const float* x    = (const float*)d_in[0];
  const float* h    = (const float*)d_in[1];
  const float* Wx   = (const float*)d_in[2];
  const float* Wdt  = (const float*)d_in[3];
  const float* bdt  = (const float*)d_in[4];
  const float* Alog = (const float*)d_in[5];
  const float* Dv   = (const float*)d_in[6];
  const float* Wout = (const float*)d_in[7];
  float* out = (float*)d_out;

  // ---- workspace layout (all 16B-aligned) ----
  char* ws = (char*)d_ws;
  size_t off = 0;
  auto alloc = [&](size_t bytes) { char* p = ws + off; off += (bytes + 255) & ~(size_t)255; return p; };
  float* xp    = (float*)alloc((size_t)BATCH * NPROJ * 4);            // 1.18 MB
  float* xpP   = (float*)alloc((size_t)16 * BATCH * NPROJ * 4);       // 18.9 MB (stage-1 partials)
  float* dP    = (float*)alloc((size_t)2 * BATCH * DMODEL * 4);       // 33.6 MB (stage-2 partials)
  float* yP    = (float*)alloc((size_t)4 * BATCH * DMODEL * 4);       // 67.1 MB (stage-4 partials)
  short* ypre  = (short*)alloc((size_t)BATCH * DMODEL * 2);           // 8.4 MB
  short* xH    = (short*)alloc((size_t)BATCH * DMODEL * 2);
  short* xL    = (short*)alloc((size_t)BATCH * DMODEL * 2);
  short* WxH   = (short*)alloc((size_t)384 * DMODEL * 2);             // padded 288->384 rows
  short* WxL   = (short*)alloc((size_t)384 * DMODEL * 2);
  short* WdtH  = (short*)alloc((size_t)DMODEL * DTRANK * 2);
  short* WdtL  = (short*)alloc((size_t)DMODEL * DTRANK * 2);
  short* xpH   = (short*)alloc((size_t)BATCH * DTRANK * 2);
  short* xpL   = (short*)alloc((size_t)BATCH * DTRANK * 2);
  short* WoutH = (short*)alloc((size_t)DMODEL * DMODEL * 2);          // 33.6 MB

  // ---- operand conversions (independent of each other) ----
  cvt_hilo<true><<<dim3((BATCH * DMODEL / 8 + 255) / 256), 256, 0, stream>>>(x, xH, xL, BATCH * DMODEL / 8);
  cvt_hilo<true><<<dim3((NPROJ * DMODEL / 8 + 255) / 256), 256, 0, stream>>>(Wx, WxH, WxL, NPROJ * DMODEL / 8);
  cvt_hilo<true><<<dim3((DMODEL * DTRANK / 8 + 255) / 256), 256, 0, stream>>>(Wdt, WdtH, WdtL, DMODEL * DTRANK / 8);
  cvt_hilo<false><<<dim3((DMODEL * DMODEL / 8 + 255) / 256), 256, 0, stream>>>(Wout, WoutH, nullptr, DMODEL * DMODEL / 8);

  // stage 1: xp = x @ Wx^T  (split-K=16 partials, hi/lo split accuracy) -> reduce
  gemm_lds<true><<<dim3(3, 8, 16), 256, 0, stream>>>(
      xH, xL, DMODEL, WxH, WxL, DMODEL, NPROJ, xpP, NPROJ, (size_t)BATCH * NPROJ, 256);
  reduce_add<16><<<dim3(BATCH * NPROJ / 4 / 256), 256, 0, stream>>>(
      xpP, (size_t)BATCH * NPROJ, xp, BATCH * NPROJ / 4);

  // slice+convert xp[:, :256] to hi/lo
  cvt_xp<<<dim3(BATCH * DTRANK / 8 / 256), 256, 0, stream>>>(xp, xpH, xpL);

  // stage 2: delta_raw partials = xp[:, :256] @ Wdt^T  (split-K=2; softplus+bias
  // and the partial fold happen inside ssm_update, elementwise-exact)
  gemm_lds<true><<<dim3(32, 8, 2), 256, 0, stream>>>(
      xpH, xpL, DTRANK, WdtH, WdtL, DTRANK, DMODEL, dP, DMODEL, (size_t)BATCH * DMODEL, 128);

  // stage 3: h_new (-> out tail) + y_pre bf16
  ssm_update<<<dim3(16, BATCH), 256, 0, stream>>>(x, h, xp, dP, bdt, Alog, Dv, out, ypre);

  // stage 4: y partials = y_pre @ Wout^T (plain bf16, split-K=4) -> reduce into out
  gemm_lds<false><<<dim3(32, 8, 4), 256, 0, stream>>>(
      ypre, nullptr, DMODEL, WoutH, nullptr, DMODEL, DMODEL, yP, DMODEL, (size_t)BATCH * DMODEL, 1024);
  reduce_add<4><<<dim3(BATCH * DMODEL / 4 / 256), 256, 0, stream>>>(
      yP, (size_t)BATCH * DMODEL, out, BATCH * DMODEL / 4);
}